// Round 10
// baseline (359.066 us; speedup 1.0000x reference)
//
#include <hip/hip_runtime.h>

typedef __attribute__((ext_vector_type(8))) short short8;
typedef __attribute__((ext_vector_type(4))) float floatx4;

#define NCH 294         // chunks per layer
#define CH 8192         // edges per chunk
#define NB 196          // coarse buckets (1024 keys each)
#define NKP 200704      // padded key count (NB*1024)

__device__ __forceinline__ unsigned short f2bf(float f) {
  unsigned u = __float_as_uint(f);
  u += 0x7FFFu + ((u >> 16) & 1u);
  return (unsigned short)(u >> 16);
}
__device__ __forceinline__ float blo(unsigned x) { return __uint_as_float(x << 16); }
__device__ __forceinline__ float bhi(unsigned x) { return __uint_as_float(x & 0xFFFF0000u); }
__device__ __forceinline__ unsigned getdw(const uint4& v, int k) {
  return k == 0 ? v.x : k == 1 ? v.y : k == 2 ? v.z : v.w;
}
__device__ __forceinline__ unsigned getdw2(const uint2& v, int k) {
  return k == 0 ? v.x : v.y;
}

// ---- fused prep (feat->bf16, W transposes) + per-chunk bucket histogram ----
__global__ __launch_bounds__(1024) void prep_count_k(
    const float* __restrict__ feat, const float* __restrict__ W1,
    const float* __restrict__ W2, const int* __restrict__ ed1,
    const int* __restrict__ ed2, unsigned short* __restrict__ featb,
    unsigned short* __restrict__ w1t, unsigned short* __restrict__ w2t,
    int* __restrict__ ghist) {
  __shared__ int h[NB];
  if (blockIdx.x < 2 * NCH) {            // count role
    int tid = threadIdx.x;
    int layer = blockIdx.x >= NCH;
    int c = blockIdx.x - layer * NCH;
    const int* ed = layer ? ed2 : ed1;
    if (tid < NB) h[tid] = 0;
    __syncthreads();
    int j0 = c * CH;
    for (int it = 0; it < CH / 1024; ++it) {
      int j = j0 + it * 1024 + tid;
      if (j < 2400000) atomicAdd(&h[(ed[j] * 4 + j / 800000) >> 10], 1);
    }
    __syncthreads();
    if (tid < NB) ghist[(layer * NB + tid) * NCH + c] = h[tid];
  } else {                               // prep role
    int tid = (blockIdx.x - 2 * NCH) * 1024 + threadIdx.x;
    if (tid < 1600000) {
      float4 v = ((const float4*)feat)[tid];
      ushort4 o;
      o.x = f2bf(v.x); o.y = f2bf(v.y); o.z = f2bf(v.z); o.w = f2bf(v.w);
      ((ushort4*)featb)[tid] = o;
    } else if (tid < 1600000 + 49152) {
      int t = tid - 1600000;
      int r = t >> 14, rem = t & 16383, n = rem >> 7, k = rem & 127;
      w1t[t] = f2bf(W1[(r << 14) + (k << 7) + n]);
    } else if (tid < 1600000 + 49152 + 24576) {
      int t = tid - 1649152;
      int r = t >> 13, rem = t & 8191, n = rem >> 7, k = rem & 127;
      w2t[t] = f2bf(W2[(r << 13) + (k << 6) + n]);
    }
  }
}

// ---- per-(layer,bucket) scan of 294 chunk counts -> gpre (counts kept) ----
__global__ __launch_bounds__(320) void scanb_k(const int* __restrict__ ghist,
                                               int* __restrict__ gpre,
                                               int* __restrict__ btot) {
  __shared__ int wsum[5];
  int t = threadIdx.x, lane = t & 63, w = t >> 6;
  int base = blockIdx.x * NCH;
  int v = (t < NCH) ? ghist[base + t] : 0;
  int inc = v;
#pragma unroll
  for (int o = 1; o < 64; o <<= 1) {
    int u = __shfl_up(inc, o);
    if (lane >= o) inc += u;
  }
  if (lane == 63) wsum[w] = inc;
  __syncthreads();
  int woff = 0;
#pragma unroll
  for (int k = 0; k < 5; ++k) if (k < w) woff += wsum[k];
  if (t < NCH) gpre[base + t] = woff + inc - v;
  if (t == 319) btot[blockIdx.x] = woff + inc;
}

// ---- single-wave scan of the 392 bucket totals -> bucket bases + sentinel ----
__global__ __launch_bounds__(64) void scanc_k(const int* __restrict__ btot,
                                              int* __restrict__ bbase) {
  int lane = threadIdx.x;
  int carry = 0;
  for (int g0 = 0; g0 < 448; g0 += 64) {
    int i = g0 + lane;
    int v = (i < 2 * NB) ? btot[i] : 0;
    int inc = v;
#pragma unroll
    for (int o = 1; o < 64; o <<= 1) {
      int u = __shfl_up(inc, o);
      if (lane >= o) inc += u;
    }
    if (i < 2 * NB) bbase[i] = carry + inc - v;
    carry += __shfl(inc, 63);
  }
  if (lane == 0) bbase[2 * NB] = carry;
}

// ---- LDS-staged scatter: bucket-sort whole 32KB chunk in LDS, then flush
// bucket-runs with consecutive lanes -> full-line coalesced global stores ----
__global__ __launch_bounds__(1024) void scatter_k(
    const int* __restrict__ es1, const int* __restrict__ ed1,
    const int* __restrict__ es2, const int* __restrict__ ed2,
    const int* __restrict__ ghist, const int* __restrict__ gpre,
    const int* __restrict__ bbase, unsigned* __restrict__ sorted) {
  __shared__ unsigned ent[CH];          // 32 KB
  __shared__ unsigned char bid[CH];     // 8 KB
  __shared__ int lstart[NB], lcur[NB], gb[NB];
  int tid = threadIdx.x;
  int layer = blockIdx.x >= NCH;
  int c = blockIdx.x - layer * NCH;
  const int* es = layer ? es2 : es1;
  const int* ed = layer ? ed2 : ed1;
  int rowb = layer * NB;
  if (tid < NB) {
    int idx = (rowb + tid) * NCH + c;
    lstart[tid] = ghist[idx];           // counts (temporarily)
    gb[tid] = bbase[rowb + tid] + gpre[idx];
  }
  __syncthreads();
  if (tid < 64) {                       // wave scan counts -> exclusive prefix
    int carry = 0;
    for (int g0 = 0; g0 < NB; g0 += 64) {
      int i = g0 + tid;
      int h = (i < NB) ? lstart[i] : 0;
      int inc = h;
#pragma unroll
      for (int o = 1; o < 64; o <<= 1) {
        int u = __shfl_up(inc, o);
        if (tid >= o) inc += u;
      }
      if (i < NB) {
        int e = carry + inc - h;
        lstart[i] = e;
        lcur[i] = e;
      }
      carry += __shfl(inc, 63);
    }
  }
  __syncthreads();
  int j0 = c * CH;
  int cn = 2400000 - j0;
  if (cn > CH) cn = CH;
  for (int it = 0; it < CH / 1024; ++it) {
    int jj = it * 1024 + tid;
    if (jj < cn) {
      int j = j0 + jj;
      int key = ed[j] * 4 + j / 800000;
      int b = key >> 10;
      int pos = atomicAdd(&lcur[b], 1);
      ent[pos] = (unsigned)es[j] | ((unsigned)(key & 1023) << 16);
      bid[pos] = (unsigned char)b;
    }
  }
  __syncthreads();
  for (int i = tid; i < cn; i += 1024) {
    int b = bid[i];
    sorted[gb[b] + (i - lstart[b])] = ent[i];
  }
}

// ---- per-bucket micro-sort: bucket-grouped -> key-sorted ushort srcs + off/cnt ----
__global__ __launch_bounds__(1024) void sortb_k(
    const int* __restrict__ bbase, const unsigned* __restrict__ sorted,
    unsigned short* __restrict__ sorted2, int* __restrict__ offk,
    int* __restrict__ cntk) {
  __shared__ int hist[1024], cur[1024];
  int tid = threadIdx.x;
  int layer = blockIdx.x >= NB;
  int b = blockIdx.x - layer * NB;
  int start = bbase[blockIdx.x];
  int end = bbase[blockIdx.x + 1];
  hist[tid] = 0;
  __syncthreads();
  for (int e = start + tid; e < end; e += 1024)
    atomicAdd(&hist[sorted[e] >> 16], 1);
  __syncthreads();
  if (tid < 64) {
    int carry = 0;
    for (int g0 = 0; g0 < 1024; g0 += 64) {
      int h = hist[g0 + tid];
      int inc = h;
#pragma unroll
      for (int o = 1; o < 64; o <<= 1) {
        int u = __shfl_up(inc, o);
        if (tid >= o) inc += u;
      }
      int excl = carry + inc - h;
      cur[g0 + tid] = excl;
      int lb = layer * NKP + (b << 10) + g0 + tid;
      offk[lb] = start + excl;
      cntk[lb] = h;
      carry += __shfl(inc, 63);
    }
  }
  __syncthreads();
  for (int e = start + tid; e < end; e += 1024) {
    unsigned v = sorted[e];
    int p = atomicAdd(&cur[v >> 16], 1);
    sorted2[start + p] = (unsigned short)(v & 0xFFFFu);
  }
}

// ---- build per-edge (r*50000+src) for layer 2 into the dead `sorted` buffer
// (no readers of `sorted` after sortb_k). Key-parallel: avg 12 edges/key. ----
__global__ __launch_bounds__(256) void mkrsrc_k(
    const int* __restrict__ offk, const int* __restrict__ cntk,
    const unsigned short* __restrict__ sorted2, unsigned* __restrict__ rsrc) {
  int k = blockIdx.x * 256 + threadIdx.x;
  if (k >= NKP) return;
  int base = offk[NKP + k], n = cntk[NKP + k];
  unsigned radd = (unsigned)(k & 3) * 50000u;
  for (int i = 0; i < n; ++i)
    rsrc[base + i - 2400000] = radd + (unsigned)sorted2[base + i];
}

// ---- layer-1 agg (round-7 verified: 69.2us, 0 bank conflicts, VGPR 64):
// MFMA segmented mean, XOR-swizzled fragment LDS, 2-deep gather prefetch.
// [3-deep (r9) regressed: VGPR 84 -> occupancy 27%, reverted.] ----
__global__ __launch_bounds__(256, 4) void agg1_k(
    const int* __restrict__ offk, const int* __restrict__ cntk,
    const unsigned short* __restrict__ sorted2,
    const unsigned short* __restrict__ featb,
    unsigned short* __restrict__ s1m) {
  __shared__ uint4 stage4[4][512];      // 4 waves x 8192 B
  int lane = threadIdx.x & 63;
  int w = threadIdx.x >> 6;
  int grp = blockIdx.x * 4 + w;         // 12500 groups of 16 keys (4 nodes)
  if (grp >= 12500) return;
  int K0 = grp << 4;
  int m = lane & 15;
  int g4 = lane >> 4;
  int om = offk[K0 + m];
  int om1 = offk[K0 + m + 1];           // contiguous across bucket boundaries
  int nm = om1 - om;
  int s = __builtin_amdgcn_readfirstlane(om);
  int e = __shfl(om1, 15);
  int total = e - s;

  floatx4 acc[8];
#pragma unroll
  for (int t = 0; t < 8; ++t) acc[t] = (floatx4){0.f, 0.f, 0.f, 0.f};

  char* wbase = (char*)&stage4[w][0];
  // write lane (m,g4), phase c: fragment ch=8m+c
  unsigned woff = ((unsigned)g4 << 11) + ((unsigned)m << 7) +
                  ((unsigned)(m & 7) << 4);
  // read lane (m,g4), phase T: fragment ch=16T+m
  unsigned roff = ((unsigned)g4 << 11) + ((unsigned)(m >> 3) << 7) +
                  ((unsigned)((m >> 3) ^ (m & 7)) << 4);
  int cb = m << 4;                      // byte offset within a 256B feat row
  int relc = s + (g4 << 3) - om;        // A-indicator base: edge(k=8*g4) - om

  if (total > 0) {
    int elast = e - 1;
    int nch = (total + 31) >> 5;

#define AGG_GATHER(dst, cbase_)                                                \
  _Pragma("unroll") for (int i = 0; i < 8; ++i) {                              \
    int eidx = (cbase_) + (g4 << 3) + i;                                       \
    if (eidx > elast) eidx = elast;                                            \
    int sidx = sorted2[eidx];                                                  \
    dst[i] = *(const uint4*)((const char*)featb + (sidx << 8) + cb);           \
  }

#define AGG_BODY(d, c_)                                                        \
  do {                                                                         \
    _Pragma("unroll") for (int c = 0; c < 8; ++c) {                            \
      unsigned sel = (c & 1) ? 0x07060302u : 0x05040100u;                      \
      int k = c >> 1;                                                          \
      uint4 G;                                                                 \
      G.x = __builtin_amdgcn_perm(getdw(d[1], k), getdw(d[0], k), sel);        \
      G.y = __builtin_amdgcn_perm(getdw(d[3], k), getdw(d[2], k), sel);        \
      G.z = __builtin_amdgcn_perm(getdw(d[5], k), getdw(d[4], k), sel);        \
      G.w = __builtin_amdgcn_perm(getdw(d[7], k), getdw(d[6], k), sel);        \
      *(uint4*)(wbase + (woff ^ (c << 4))) = G;                                \
    }                                                                          \
    int rel = relc + ((c_) << 5);                                              \
    union { unsigned u[4]; short8 s8; } cva;                                   \
    _Pragma("unroll") for (int jj = 0; jj < 4; ++jj) {                         \
      unsigned lo = ((unsigned)(rel + 2 * jj) < (unsigned)nm) ? 0x3F80u : 0u;  \
      unsigned hi =                                                            \
          ((unsigned)(rel + 2 * jj + 1) < (unsigned)nm) ? 0x3F800000u : 0u;    \
      cva.u[jj] = lo | hi;                                                     \
    }                                                                          \
    short8 afrag = cva.s8;                                                     \
    _Pragma("unroll") for (int T = 0; T < 8; ++T) {                            \
      short8 bf = *(const short8*)(                                            \
          wbase + (roff ^ ((unsigned)((T << 8) | (((2 * T) & 7) << 4)))));     \
      acc[T] =                                                                 \
          __builtin_amdgcn_mfma_f32_16x16x32_bf16(afrag, bf, acc[T], 0, 0, 0); \
    }                                                                          \
  } while (0)

    uint4 dA[8], dB[8];
    AGG_GATHER(dA, s)
    for (int c = 0; c < nch; c += 2) {
      int nx = (c + 1 < nch) ? c + 1 : nch - 1;
      AGG_GATHER(dB, s + (nx << 5))
      AGG_BODY(dA, c);
      if (c + 1 < nch) {
        int nx2 = (c + 2 < nch) ? c + 2 : nch - 1;
        AGG_GATHER(dA, s + (nx2 << 5))
        AGG_BODY(dB, c + 1);
      }
    }
#undef AGG_BODY
#undef AGG_GATHER
  }
  // ---- epilogue: scale rows by 1/max(n,1) in f32, store bf16.
  // C layout: row(key)=g4*4+reg, col(ch)=T*16+m. reg==3 is the dummy slot.
  int vbase = grp << 2;
#pragma unroll
  for (int reg = 0; reg < 3; ++reg) {
    int np = __shfl(nm, (g4 << 2) + reg);
    float inv = 1.0f / fmaxf((float)np, 1.0f);
    unsigned short* orow = s1m + (((reg * 50000 + vbase + g4) << 7) + m);
#pragma unroll
    for (int t = 0; t < 8; ++t)
      orow[t << 4] = f2bf(acc[t][reg] * inv);
  }
}

// ---- fused GEMM1+GEMM2, persistent weights in registers, grid-stride M ----
__global__ __launch_bounds__(512) void gemm12_k(
    const unsigned short* __restrict__ s1m, const int* __restrict__ cntk,
    const unsigned short* __restrict__ w1t, const float* __restrict__ b1,
    const unsigned short* __restrict__ w2t, const float* __restrict__ b2,
    unsigned short* __restrict__ wh2) {
  __shared__ unsigned short hs[2][16 * 136];
  int lane = threadIdx.x & 63;
  int w = threadIdx.x >> 6;             // 0..7
  int m16 = lane & 15, kg = lane >> 4;
  int orow = kg << 2;

  short8 B1[12];
#pragma unroll
  for (int ks = 0; ks < 12; ++ks) {
    int r = ks >> 2;
    int k0 = ((ks & 3) << 5) + (kg << 3);
    int n = (w << 4) + m16;
    B1[ks] = *(const short8*)(w1t + (r << 14) + (n << 7) + k0);
  }
  int fa = w, fb = w + 8;
  int cola = (fa << 4) + m16, colb = (fb << 4) + m16;
  int ra = cola >> 6, c0a = cola & 63;
  int rb = colb >> 6, c0b = colb & 63;
  short8 B2a[4], B2b[4];
#pragma unroll
  for (int ks = 0; ks < 4; ++ks) {
    int k0 = (ks << 5) + (kg << 3);
    B2a[ks] = *(const short8*)(w2t + (ra << 13) + (c0a << 7) + k0);
    if (w < 4)
      B2b[ks] = *(const short8*)(w2t + (rb << 13) + (c0b << 7) + k0);
  }
  int col1 = (w << 4) + m16;
  float bb0 = b1[col1], bb1 = b1[128 + col1], bb2 = b1[256 + col1];
  float bva = b2[(ra << 6) + c0a];
  float bvb = (w < 4) ? b2[(rb << 6) + c0b] : 0.f;

  const floatx4 fzero = {0.f, 0.f, 0.f, 0.f};
  int p = 0;
  for (int t = blockIdx.x; t < 3125; t += 512) {
    int rbase = t << 4;
    int anode = rbase + m16;
    floatx4 acc1 = fzero;
#pragma unroll
    for (int ks = 0; ks < 12; ++ks) {
      int r = ks >> 2;
      int k0 = ((ks & 3) << 5) + (kg << 3);
      short8 af = *(const short8*)(s1m + ((r * 50000 + anode) << 7) + k0);
      acc1 = __builtin_amdgcn_mfma_f32_16x16x32_bf16(af, B1[ks], acc1, 0, 0, 0);
    }
#pragma unroll
    for (int reg = 0; reg < 4; ++reg) {
      int nd = rbase + orow + reg;
      float v = acc1[reg] + (cntk[nd * 4 + 0] ? bb0 : 0.f) +
                (cntk[nd * 4 + 1] ? bb1 : 0.f) + (cntk[nd * 4 + 2] ? bb2 : 0.f);
      v = (v >= 0.f) ? v : 0.01f * v;
      hs[p][(orow + reg) * 136 + col1] = f2bf(v);
    }
    __syncthreads();

    floatx4 acc2a = fzero, acc2b = fzero;
#pragma unroll
    for (int ks = 0; ks < 4; ++ks) {
      int k0 = (ks << 5) + (kg << 3);
      short8 af = *(const short8*)(&hs[p][m16 * 136 + k0]);
      acc2a = __builtin_amdgcn_mfma_f32_16x16x32_bf16(af, B2a[ks], acc2a, 0, 0, 0);
      if (w < 4)
        acc2b = __builtin_amdgcn_mfma_f32_16x16x32_bf16(af, B2b[ks], acc2b, 0, 0, 0);
    }
#pragma unroll
    for (int reg = 0; reg < 4; ++reg) {
      int nd = rbase + orow + reg;
      wh2[((ra * 50000 + nd) << 6) + c0a] = f2bf(acc2a[reg] + bva);
      if (w < 4)
        wh2[((rb * 50000 + nd) << 6) + c0b] = f2bf(acc2b[reg] + bvb);
    }
    p ^= 1;
  }
}

// ---- layer-2 agg v2: MFMA segmented mean (port of agg1 v8, 64-ch rows).
// One wave per 16 keys (4 nodes). Gather via precomputed rsrc=r*50000+src
// (wh2 rows are etype-dependent). Per 32-edge chunk: lane (m,g4) loads uint2
// (4 ch at block m) for 8 edges, 16 perms -> 4 fragments, XOR-swizzled LDS
// (write quads c^{0..7}, read quads m^(2T&7): 8-distinct both ways), 4 MFMA.
// Epilogue: out[v] = sum_r acc[T][r]*inv_r -- 3 in-lane FMAs, f32 store. ----
__global__ __launch_bounds__(256, 4) void agg2f_k(
    const int* __restrict__ offk, const int* __restrict__ cntk,
    const unsigned* __restrict__ rsrc, const unsigned short* __restrict__ wh2,
    float* __restrict__ out) {
  __shared__ uint4 stage2[4][256];      // 4 waves x 4096 B
  int lane = threadIdx.x & 63;
  int w = threadIdx.x >> 6;
  int grp = blockIdx.x * 4 + w;         // 12500 groups of 16 keys (4 nodes)
  if (grp >= 12500) return;
  int K0 = NKP + (grp << 4);
  int m = lane & 15;
  int g4 = lane >> 4;
  int om = offk[K0 + m];
  int om1 = offk[K0 + m + 1];
  int nm = om1 - om;
  int s = __builtin_amdgcn_readfirstlane(om);
  int e = __shfl(om1, 15);
  int total = e - s;

  floatx4 acc[4];
#pragma unroll
  for (int t = 0; t < 4; ++t) acc[t] = (floatx4){0.f, 0.f, 0.f, 0.f};

  char* wbase = (char*)&stage2[w][0];
  // write lane (m,g4), phase c: fragment ch=4m+c: a=m>>1, b=4(m&1)+c
  unsigned woff = ((unsigned)g4 << 10) + ((unsigned)(m >> 1) << 7) +
                  ((unsigned)((m >> 1) ^ ((m & 1) << 2)) << 4);
  // read lane (m,g4), phase T: fragment ch=16T+m: a=2T+(m>>3), b=m&7
  unsigned roff = ((unsigned)g4 << 10) + ((unsigned)(m >> 3) << 7) +
                  ((unsigned)((m >> 3) ^ (m & 7)) << 4);
  int cb = m << 3;                      // byte offset within a 128B wh2 row
  int relc = s + (g4 << 3) - om;

  if (total > 0) {
    int elast = e - 1;
    int nch = (total + 31) >> 5;

#define AG2_GATHER(dst, cbase_)                                                \
  _Pragma("unroll") for (int i = 0; i < 8; ++i) {                              \
    int eidx = (cbase_) + (g4 << 3) + i;                                       \
    if (eidx > elast) eidx = elast;                                            \
    unsigned rs = rsrc[eidx - 2400000];                                        \
    dst[i] = *(const uint2*)((const char*)wh2 + ((unsigned long long)rs << 7) + cb); \
  }

#define AG2_BODY(d, c_)                                                        \
  do {                                                                         \
    _Pragma("unroll") for (int c = 0; c < 4; ++c) {                            \
      unsigned sel = (c & 1) ? 0x07060302u : 0x05040100u;                      \
      int k = c >> 1;                                                          \
      uint4 G;                                                                 \
      G.x = __builtin_amdgcn_perm(getdw2(d[1], k), getdw2(d[0], k), sel);      \
      G.y = __builtin_amdgcn_perm(getdw2(d[3], k), getdw2(d[2], k), sel);      \
      G.z = __builtin_amdgcn_perm(getdw2(d[5], k), getdw2(d[4], k), sel);      \
      G.w = __builtin_amdgcn_perm(getdw2(d[7], k), getdw2(d[6], k), sel);      \
      *(uint4*)(wbase + (woff ^ (c << 4))) = G;                                \
    }                                                                          \
    int rel = relc + ((c_) << 5);                                              \
    union { unsigned u[4]; short8 s8; } cva;                                   \
    _Pragma("unroll") for (int jj = 0; jj < 4; ++jj) {                         \
      unsigned lo = ((unsigned)(rel + 2 * jj) < (unsigned)nm) ? 0x3F80u : 0u;  \
      unsigned hi =                                                            \
          ((unsigned)(rel + 2 * jj + 1) < (unsigned)nm) ? 0x3F800000u : 0u;    \
      cva.u[jj] = lo | hi;                                                     \
    }                                                                          \
    short8 afrag = cva.s8;                                                     \
    _Pragma("unroll") for (int T = 0; T < 4; ++T) {                            \
      short8 bf = *(const short8*)(                                            \
          wbase + (roff ^ ((unsigned)((T << 8) | (((2 * T) & 7) << 4)))));     \
      acc[T] =                                                                 \
          __builtin_amdgcn_mfma_f32_16x16x32_bf16(afrag, bf, acc[T], 0, 0, 0); \
    }                                                                          \
  } while (0)

    uint2 dA[8], dB[8];
    AG2_GATHER(dA, s)
    for (int c = 0; c < nch; c += 2) {
      int nx = (c + 1 < nch) ? c + 1 : nch - 1;
      AG2_GATHER(dB, s + (nx << 5))
      AG2_BODY(dA, c);
      if (c + 1 < nch) {
        int nx2 = (c + 2 < nch) ? c + 2 : nch - 1;
        AG2_GATHER(dA, s + (nx2 << 5))
        AG2_BODY(dB, c + 1);
      }
    }
#undef AG2_BODY
#undef AG2_GATHER
  }
  // ---- epilogue: C row(key)=g4*4+reg, col(ch)=T*16+m; node v=grp*4+g4,
  // r=reg (reg==3 dummy). out[v][ch] = sum_r acc[T][r]/max(n_r,1), f32. ----
  int v = (grp << 2) + g4;
  float inv0 = 1.0f / fmaxf((float)__shfl(nm, (g4 << 2) + 0), 1.0f);
  float inv1 = 1.0f / fmaxf((float)__shfl(nm, (g4 << 2) + 1), 1.0f);
  float inv2 = 1.0f / fmaxf((float)__shfl(nm, (g4 << 2) + 2), 1.0f);
#pragma unroll
  for (int T = 0; T < 4; ++T)
    out[(v << 6) + (T << 4) + m] =
        acc[T][0] * inv0 + acc[T][1] * inv1 + acc[T][2] * inv2;
}

extern "C" void kernel_launch(void* const* d_in, const int* in_sizes, int n_in,
                              void* d_out, int out_size, void* d_ws, size_t ws_size,
                              hipStream_t stream) {
  const float* feat = (const float*)d_in[0];
  const float* W1   = (const float*)d_in[1];
  const float* b1   = (const float*)d_in[2];
  const float* W2   = (const float*)d_in[3];
  const float* b2   = (const float*)d_in[4];
  const int* es1 = (const int*)d_in[5];
  const int* ed1 = (const int*)d_in[6];
  const int* es2 = (const int*)d_in[7];
  const int* ed2 = (const int*)d_in[8];

  char* ws = (char*)d_ws;
  int* ghist           = (int*)(ws + 0);             // 460,992 B (counts)
  int* gpre            = (int*)(ws + 460992);        // 460,992 B (prefixes)
  int* btot            = (int*)(ws + 921984);        // 392 ints
  int* bbase           = (int*)(ws + 923552);        // 393 ints
  unsigned* sorted     = (unsigned*)(ws + 925184);   // 19.2 MB (reused as rsrc)
  unsigned short* sorted2 = (unsigned short*)(ws + 20125184); // 9.6 MB
  int* offk            = (int*)(ws + 29725184);      // 2*200704 ints
  int* cntk            = (int*)(ws + 31330816);      // 2*200704 ints
  unsigned short* featb = (unsigned short*)(ws + 32936448);  // 12.8 MB
  unsigned short* s1m   = (unsigned short*)(ws + 45736448);  // 38.4 MB
  unsigned short* wh2   = (unsigned short*)(ws + 84136448);  // 19.2 MB
  unsigned short* w1t   = (unsigned short*)(ws + 103336448); // 98,304 B
  unsigned short* w2t   = (unsigned short*)(ws + 103434752); // 49,152 B

  prep_count_k<<<2 * NCH + 1635, 1024, 0, stream>>>(feat, W1, W2, ed1, ed2,
                                                    featb, w1t, w2t, ghist);
  scanb_k<<<2 * NB, 320, 0, stream>>>(ghist, gpre, btot);
  scanc_k<<<1, 64, 0, stream>>>(btot, bbase);
  scatter_k<<<2 * NCH, 1024, 0, stream>>>(es1, ed1, es2, ed2, ghist, gpre,
                                          bbase, sorted);
  sortb_k<<<2 * NB, 1024, 0, stream>>>(bbase, sorted, sorted2, offk, cntk);
  mkrsrc_k<<<784, 256, 0, stream>>>(offk, cntk, sorted2, sorted);
  agg1_k<<<3125, 256, 0, stream>>>(offk, cntk, sorted2, featb, s1m);
  gemm12_k<<<512, 512, 0, stream>>>(s1m, cntk, w1t, b1, w2t, b2, wh2);
  agg2f_k<<<3125, 256, 0, stream>>>(offk, cntk, sorted, wh2, (float*)d_out);
}

// Round 11
// 330.302 us; speedup vs baseline: 1.0871x; 1.0871x over previous
//
#include <hip/hip_runtime.h>

typedef __attribute__((ext_vector_type(8))) short short8;
typedef __attribute__((ext_vector_type(4))) float floatx4;

#define NCH 294         // chunks per layer
#define CH 8192         // edges per chunk
#define NB 196          // coarse buckets (1024 keys each)
#define NKP 200704      // padded key count (NB*1024)
#define SCAP 15360      // sortb LDS staging cap (mean 12288 + 27 sigma)

__device__ __forceinline__ unsigned short f2bf(float f) {
  unsigned u = __float_as_uint(f);
  u += 0x7FFFu + ((u >> 16) & 1u);
  return (unsigned short)(u >> 16);
}
__device__ __forceinline__ float blo(unsigned x) { return __uint_as_float(x << 16); }
__device__ __forceinline__ float bhi(unsigned x) { return __uint_as_float(x & 0xFFFF0000u); }
__device__ __forceinline__ unsigned getdw(const uint4& v, int k) {
  return k == 0 ? v.x : k == 1 ? v.y : k == 2 ? v.z : v.w;
}

// ---- fused prep (feat->bf16, W transposes) + per-chunk bucket histogram ----
__global__ __launch_bounds__(1024) void prep_count_k(
    const float* __restrict__ feat, const float* __restrict__ W1,
    const float* __restrict__ W2, const int* __restrict__ ed1,
    const int* __restrict__ ed2, unsigned short* __restrict__ featb,
    unsigned short* __restrict__ w1t, unsigned short* __restrict__ w2t,
    int* __restrict__ ghist) {
  __shared__ int h[NB];
  if (blockIdx.x < 2 * NCH) {            // count role
    int tid = threadIdx.x;
    int layer = blockIdx.x >= NCH;
    int c = blockIdx.x - layer * NCH;
    const int* ed = layer ? ed2 : ed1;
    if (tid < NB) h[tid] = 0;
    __syncthreads();
    int j0 = c * CH;
    for (int it = 0; it < CH / 1024; ++it) {
      int j = j0 + it * 1024 + tid;
      if (j < 2400000) atomicAdd(&h[(ed[j] * 4 + j / 800000) >> 10], 1);
    }
    __syncthreads();
    if (tid < NB) ghist[(layer * NB + tid) * NCH + c] = h[tid];
  } else {                               // prep role
    int tid = (blockIdx.x - 2 * NCH) * 1024 + threadIdx.x;
    if (tid < 1600000) {
      float4 v = ((const float4*)feat)[tid];
      ushort4 o;
      o.x = f2bf(v.x); o.y = f2bf(v.y); o.z = f2bf(v.z); o.w = f2bf(v.w);
      ((ushort4*)featb)[tid] = o;
    } else if (tid < 1600000 + 49152) {
      int t = tid - 1600000;
      int r = t >> 14, rem = t & 16383, n = rem >> 7, k = rem & 127;
      w1t[t] = f2bf(W1[(r << 14) + (k << 7) + n]);
    } else if (tid < 1600000 + 49152 + 24576) {
      int t = tid - 1649152;
      int r = t >> 13, rem = t & 8191, n = rem >> 7, k = rem & 127;
      w2t[t] = f2bf(W2[(r << 13) + (k << 6) + n]);
    }
  }
}

// ---- per-(layer,bucket) scan of 294 chunk counts -> gpre (counts kept) ----
__global__ __launch_bounds__(320) void scanb_k(const int* __restrict__ ghist,
                                               int* __restrict__ gpre,
                                               int* __restrict__ btot) {
  __shared__ int wsum[5];
  int t = threadIdx.x, lane = t & 63, w = t >> 6;
  int base = blockIdx.x * NCH;
  int v = (t < NCH) ? ghist[base + t] : 0;
  int inc = v;
#pragma unroll
  for (int o = 1; o < 64; o <<= 1) {
    int u = __shfl_up(inc, o);
    if (lane >= o) inc += u;
  }
  if (lane == 63) wsum[w] = inc;
  __syncthreads();
  int woff = 0;
#pragma unroll
  for (int k = 0; k < 5; ++k) if (k < w) woff += wsum[k];
  if (t < NCH) gpre[base + t] = woff + inc - v;
  if (t == 319) btot[blockIdx.x] = woff + inc;
}

// ---- LDS-staged scatter: bucket-sort whole 32KB chunk in LDS, then flush
// bucket-runs with consecutive lanes -> full-line coalesced global stores.
// btot->bbase scan inlined (scanc_k eliminated). ----
__global__ __launch_bounds__(1024) void scatter_k(
    const int* __restrict__ es1, const int* __restrict__ ed1,
    const int* __restrict__ es2, const int* __restrict__ ed2,
    const int* __restrict__ ghist, const int* __restrict__ gpre,
    const int* __restrict__ btot, unsigned* __restrict__ sorted) {
  __shared__ unsigned ent[CH];          // 32 KB
  __shared__ unsigned char bid[CH];     // 8 KB
  __shared__ int lstart[NB], lcur[NB], gb[NB];
  __shared__ int bb[2 * NB + 1];
  int tid = threadIdx.x;
  int layer = blockIdx.x >= NCH;
  int c = blockIdx.x - layer * NCH;
  const int* es = layer ? es2 : es1;
  const int* ed = layer ? ed2 : ed1;
  int rowb = layer * NB;
  if (tid < 64) {                       // inline exclusive scan of btot
    int carry = 0;
    for (int g0 = 0; g0 < 448; g0 += 64) {
      int i = g0 + tid;
      int v = (i < 2 * NB) ? btot[i] : 0;
      int inc = v;
#pragma unroll
      for (int o = 1; o < 64; o <<= 1) {
        int u = __shfl_up(inc, o);
        if (tid >= o) inc += u;
      }
      if (i < 2 * NB) bb[i] = carry + inc - v;
      carry += __shfl(inc, 63);
    }
  }
  __syncthreads();
  if (tid < NB) {
    int idx = (rowb + tid) * NCH + c;
    lstart[tid] = ghist[idx];           // counts (temporarily)
    gb[tid] = bb[rowb + tid] + gpre[idx];
  }
  __syncthreads();
  if (tid < 64) {                       // wave scan counts -> exclusive prefix
    int carry = 0;
    for (int g0 = 0; g0 < NB; g0 += 64) {
      int i = g0 + tid;
      int h = (i < NB) ? lstart[i] : 0;
      int inc = h;
#pragma unroll
      for (int o = 1; o < 64; o <<= 1) {
        int u = __shfl_up(inc, o);
        if (tid >= o) inc += u;
      }
      if (i < NB) {
        int e = carry + inc - h;
        lstart[i] = e;
        lcur[i] = e;
      }
      carry += __shfl(inc, 63);
    }
  }
  __syncthreads();
  int j0 = c * CH;
  int cn = 2400000 - j0;
  if (cn > CH) cn = CH;
  for (int it = 0; it < CH / 1024; ++it) {
    int jj = it * 1024 + tid;
    if (jj < cn) {
      int j = j0 + jj;
      int key = ed[j] * 4 + j / 800000;
      int b = key >> 10;
      int pos = atomicAdd(&lcur[b], 1);
      ent[pos] = (unsigned)es[j] | ((unsigned)(key & 1023) << 16);
      bid[pos] = (unsigned char)b;
    }
  }
  __syncthreads();
  for (int i = tid; i < cn; i += 1024) {
    int b = bid[i];
    sorted[gb[b] + (i - lstart[b])] = ent[i];
  }
}

// ---- per-bucket micro-sort: bucket-grouped -> key-sorted ushort srcs + off/cnt.
// btot->bbase scan inlined; output run staged in LDS -> coalesced stores
// (cap SCAP = mean+27sigma; scattered-store fallback for safety). ----
__global__ __launch_bounds__(1024) void sortb_k(
    const int* __restrict__ btot, const unsigned* __restrict__ sorted,
    unsigned short* __restrict__ sorted2, int* __restrict__ offk,
    int* __restrict__ cntk) {
  __shared__ int hist[1024], cur[1024];
  __shared__ int bb[2 * NB + 1];
  __shared__ unsigned short sout[SCAP];
  int tid = threadIdx.x;
  if (tid < 64) {                       // inline exclusive scan of btot
    int carry = 0;
    for (int g0 = 0; g0 < 448; g0 += 64) {
      int i = g0 + tid;
      int v = (i < 2 * NB) ? btot[i] : 0;
      int inc = v;
#pragma unroll
      for (int o = 1; o < 64; o <<= 1) {
        int u = __shfl_up(inc, o);
        if (tid >= o) inc += u;
      }
      if (i < 2 * NB) bb[i] = carry + inc - v;
      carry += __shfl(inc, 63);
    }
    if (tid == 0) bb[2 * NB] = carry;
  }
  hist[tid] = 0;
  __syncthreads();
  int layer = blockIdx.x >= NB;
  int b = blockIdx.x - layer * NB;
  int start = bb[blockIdx.x];
  int end = bb[blockIdx.x + 1];
  int rl = end - start;
  for (int e = start + tid; e < end; e += 1024)
    atomicAdd(&hist[sorted[e] >> 16], 1);
  __syncthreads();
  if (tid < 64) {
    int carry = 0;
    for (int g0 = 0; g0 < 1024; g0 += 64) {
      int h = hist[g0 + tid];
      int inc = h;
#pragma unroll
      for (int o = 1; o < 64; o <<= 1) {
        int u = __shfl_up(inc, o);
        if (tid >= o) inc += u;
      }
      int excl = carry + inc - h;
      cur[g0 + tid] = excl;
      int lb = layer * NKP + (b << 10) + g0 + tid;
      offk[lb] = start + excl;
      cntk[lb] = h;
      carry += __shfl(inc, 63);
    }
  }
  __syncthreads();
  if (rl <= SCAP) {
    for (int e = start + tid; e < end; e += 1024) {
      unsigned v = sorted[e];
      int p = atomicAdd(&cur[v >> 16], 1);
      sout[p] = (unsigned short)(v & 0xFFFFu);
    }
    __syncthreads();
    for (int i = tid; i < rl; i += 1024)
      sorted2[start + i] = sout[i];
  } else {                              // unreachable for this input; safe fallback
    for (int e = start + tid; e < end; e += 1024) {
      unsigned v = sorted[e];
      int p = atomicAdd(&cur[v >> 16], 1);
      sorted2[start + p] = (unsigned short)(v & 0xFFFFu);
    }
  }
}

// ---- layer-1 agg (round-7 verified: 69.2us, 0 bank conflicts, VGPR 64):
// MFMA segmented mean, XOR-swizzled fragment LDS, 2-deep gather prefetch. ----
__global__ __launch_bounds__(256, 4) void agg1_k(
    const int* __restrict__ offk, const int* __restrict__ cntk,
    const unsigned short* __restrict__ sorted2,
    const unsigned short* __restrict__ featb,
    unsigned short* __restrict__ s1m) {
  __shared__ uint4 stage4[4][512];      // 4 waves x 8192 B
  int lane = threadIdx.x & 63;
  int w = threadIdx.x >> 6;
  int grp = blockIdx.x * 4 + w;         // 12500 groups of 16 keys (4 nodes)
  if (grp >= 12500) return;
  int K0 = grp << 4;
  int m = lane & 15;
  int g4 = lane >> 4;
  int om = offk[K0 + m];
  int om1 = offk[K0 + m + 1];           // contiguous across bucket boundaries
  int nm = om1 - om;
  int s = __builtin_amdgcn_readfirstlane(om);
  int e = __shfl(om1, 15);
  int total = e - s;

  floatx4 acc[8];
#pragma unroll
  for (int t = 0; t < 8; ++t) acc[t] = (floatx4){0.f, 0.f, 0.f, 0.f};

  char* wbase = (char*)&stage4[w][0];
  // write lane (m,g4), phase c: fragment ch=8m+c
  unsigned woff = ((unsigned)g4 << 11) + ((unsigned)m << 7) +
                  ((unsigned)(m & 7) << 4);
  // read lane (m,g4), phase T: fragment ch=16T+m
  unsigned roff = ((unsigned)g4 << 11) + ((unsigned)(m >> 3) << 7) +
                  ((unsigned)((m >> 3) ^ (m & 7)) << 4);
  int cb = m << 4;                      // byte offset within a 256B feat row
  int relc = s + (g4 << 3) - om;        // A-indicator base: edge(k=8*g4) - om

  if (total > 0) {
    int elast = e - 1;
    int nch = (total + 31) >> 5;

#define AGG_GATHER(dst, cbase_)                                                \
  _Pragma("unroll") for (int i = 0; i < 8; ++i) {                              \
    int eidx = (cbase_) + (g4 << 3) + i;                                       \
    if (eidx > elast) eidx = elast;                                            \
    int sidx = sorted2[eidx];                                                  \
    dst[i] = *(const uint4*)((const char*)featb + (sidx << 8) + cb);           \
  }

#define AGG_BODY(d, c_)                                                        \
  do {                                                                         \
    _Pragma("unroll") for (int c = 0; c < 8; ++c) {                            \
      unsigned sel = (c & 1) ? 0x07060302u : 0x05040100u;                      \
      int k = c >> 1;                                                          \
      uint4 G;                                                                 \
      G.x = __builtin_amdgcn_perm(getdw(d[1], k), getdw(d[0], k), sel);        \
      G.y = __builtin_amdgcn_perm(getdw(d[3], k), getdw(d[2], k), sel);        \
      G.z = __builtin_amdgcn_perm(getdw(d[5], k), getdw(d[4], k), sel);        \
      G.w = __builtin_amdgcn_perm(getdw(d[7], k), getdw(d[6], k), sel);        \
      *(uint4*)(wbase + (woff ^ (c << 4))) = G;                                \
    }                                                                          \
    int rel = relc + ((c_) << 5);                                              \
    union { unsigned u[4]; short8 s8; } cva;                                   \
    _Pragma("unroll") for (int jj = 0; jj < 4; ++jj) {                         \
      unsigned lo = ((unsigned)(rel + 2 * jj) < (unsigned)nm) ? 0x3F80u : 0u;  \
      unsigned hi =                                                            \
          ((unsigned)(rel + 2 * jj + 1) < (unsigned)nm) ? 0x3F800000u : 0u;    \
      cva.u[jj] = lo | hi;                                                     \
    }                                                                          \
    short8 afrag = cva.s8;                                                     \
    _Pragma("unroll") for (int T = 0; T < 8; ++T) {                            \
      short8 bf = *(const short8*)(                                            \
          wbase + (roff ^ ((unsigned)((T << 8) | (((2 * T) & 7) << 4)))));     \
      acc[T] =                                                                 \
          __builtin_amdgcn_mfma_f32_16x16x32_bf16(afrag, bf, acc[T], 0, 0, 0); \
    }                                                                          \
  } while (0)

    uint4 dA[8], dB[8];
    AGG_GATHER(dA, s)
    for (int c = 0; c < nch; c += 2) {
      int nx = (c + 1 < nch) ? c + 1 : nch - 1;
      AGG_GATHER(dB, s + (nx << 5))
      AGG_BODY(dA, c);
      if (c + 1 < nch) {
        int nx2 = (c + 2 < nch) ? c + 2 : nch - 1;
        AGG_GATHER(dA, s + (nx2 << 5))
        AGG_BODY(dB, c + 1);
      }
    }
#undef AGG_BODY
#undef AGG_GATHER
  }
  // ---- epilogue: scale rows by 1/max(n,1) in f32, store bf16.
  // C layout: row(key)=g4*4+reg, col(ch)=T*16+m. reg==3 is the dummy slot.
  int vbase = grp << 2;
#pragma unroll
  for (int reg = 0; reg < 3; ++reg) {
    int np = __shfl(nm, (g4 << 2) + reg);
    float inv = 1.0f / fmaxf((float)np, 1.0f);
    unsigned short* orow = s1m + (((reg * 50000 + vbase + g4) << 7) + m);
#pragma unroll
    for (int t = 0; t < 8; ++t)
      orow[t << 4] = f2bf(acc[t][reg] * inv);
  }
}

// ---- fused GEMM1+GEMM2, persistent weights in registers, grid-stride M ----
__global__ __launch_bounds__(512) void gemm12_k(
    const unsigned short* __restrict__ s1m, const int* __restrict__ cntk,
    const unsigned short* __restrict__ w1t, const float* __restrict__ b1,
    const unsigned short* __restrict__ w2t, const float* __restrict__ b2,
    unsigned short* __restrict__ wh2) {
  __shared__ unsigned short hs[2][16 * 136];
  int lane = threadIdx.x & 63;
  int w = threadIdx.x >> 6;             // 0..7
  int m16 = lane & 15, kg = lane >> 4;
  int orow = kg << 2;

  short8 B1[12];
#pragma unroll
  for (int ks = 0; ks < 12; ++ks) {
    int r = ks >> 2;
    int k0 = ((ks & 3) << 5) + (kg << 3);
    int n = (w << 4) + m16;
    B1[ks] = *(const short8*)(w1t + (r << 14) + (n << 7) + k0);
  }
  int fa = w, fb = w + 8;
  int cola = (fa << 4) + m16, colb = (fb << 4) + m16;
  int ra = cola >> 6, c0a = cola & 63;
  int rb = colb >> 6, c0b = colb & 63;
  short8 B2a[4], B2b[4];
#pragma unroll
  for (int ks = 0; ks < 4; ++ks) {
    int k0 = (ks << 5) + (kg << 3);
    B2a[ks] = *(const short8*)(w2t + (ra << 13) + (c0a << 7) + k0);
    if (w < 4)
      B2b[ks] = *(const short8*)(w2t + (rb << 13) + (c0b << 7) + k0);
  }
  int col1 = (w << 4) + m16;
  float bb0 = b1[col1], bb1 = b1[128 + col1], bb2 = b1[256 + col1];
  float bva = b2[(ra << 6) + c0a];
  float bvb = (w < 4) ? b2[(rb << 6) + c0b] : 0.f;

  const floatx4 fzero = {0.f, 0.f, 0.f, 0.f};
  int p = 0;
  for (int t = blockIdx.x; t < 3125; t += 512) {
    int rbase = t << 4;
    int anode = rbase + m16;
    floatx4 acc1 = fzero;
#pragma unroll
    for (int ks = 0; ks < 12; ++ks) {
      int r = ks >> 2;
      int k0 = ((ks & 3) << 5) + (kg << 3);
      short8 af = *(const short8*)(s1m + ((r * 50000 + anode) << 7) + k0);
      acc1 = __builtin_amdgcn_mfma_f32_16x16x32_bf16(af, B1[ks], acc1, 0, 0, 0);
    }
#pragma unroll
    for (int reg = 0; reg < 4; ++reg) {
      int nd = rbase + orow + reg;
      float v = acc1[reg] + (cntk[nd * 4 + 0] ? bb0 : 0.f) +
                (cntk[nd * 4 + 1] ? bb1 : 0.f) + (cntk[nd * 4 + 2] ? bb2 : 0.f);
      v = (v >= 0.f) ? v : 0.01f * v;
      hs[p][(orow + reg) * 136 + col1] = f2bf(v);
    }
    __syncthreads();

    floatx4 acc2a = fzero, acc2b = fzero;
#pragma unroll
    for (int ks = 0; ks < 4; ++ks) {
      int k0 = (ks << 5) + (kg << 3);
      short8 af = *(const short8*)(&hs[p][m16 * 136 + k0]);
      acc2a = __builtin_amdgcn_mfma_f32_16x16x32_bf16(af, B2a[ks], acc2a, 0, 0, 0);
      if (w < 4)
        acc2b = __builtin_amdgcn_mfma_f32_16x16x32_bf16(af, B2b[ks], acc2b, 0, 0, 0);
    }
#pragma unroll
    for (int reg = 0; reg < 4; ++reg) {
      int nd = rbase + orow + reg;
      wh2[((ra * 50000 + nd) << 6) + c0a] = f2bf(acc2a[reg] + bva);
      if (w < 4)
        wh2[((rb * 50000 + nd) << 6) + c0b] = f2bf(acc2b[reg] + bvb);
    }
    p ^= 1;
  }
}

// ---- layer-2 agg + final (round-7 verified): wave per node, 4 edges per
// vmem instr (uint2/16 lanes) ----
__global__ __launch_bounds__(256) void agg2f_k(
    const int* __restrict__ offk, const int* __restrict__ cntk,
    const unsigned short* __restrict__ sorted2,
    const uint2* __restrict__ wh2q, float* __restrict__ out) {
  int lane = threadIdx.x & 63;
  int q = lane >> 4, l16 = lane & 15;
  int v = blockIdx.x * 4 + (threadIdx.x >> 6);
  if (v >= 50000) return;
  const uint2* wb = wh2q + l16;
  float o0 = 0.f, o1 = 0.f, o2 = 0.f, o3 = 0.f;
#pragma unroll
  for (int r = 0; r < 3; ++r) {
    int key = NKP + v * 4 + r;
    int base = offk[key], n = cntk[key];
    const uint2* wbr = wb + ((r * 50000) << 4);
    float a0 = 0.f, a1 = 0.f, a2 = 0.f, a3 = 0.f;
    for (int jb = 0; jb < n; jb += 64) {
      int m = n - jb; if (m > 64) m = 64;
      int my = (lane < m) ? (int)sorted2[base + jb + lane] : 0;
      int k = 0;
      for (; k + 16 <= m; k += 16) {
        int i0 = __shfl(my, k + q);
        int i1 = __shfl(my, k + 4 + q);
        int i2 = __shfl(my, k + 8 + q);
        int i3 = __shfl(my, k + 12 + q);
        uint2 p0 = wbr[i0 << 4], p1 = wbr[i1 << 4];
        uint2 p2 = wbr[i2 << 4], p3 = wbr[i3 << 4];
        a0 += blo(p0.x) + blo(p1.x) + blo(p2.x) + blo(p3.x);
        a1 += bhi(p0.x) + bhi(p1.x) + bhi(p2.x) + bhi(p3.x);
        a2 += blo(p0.y) + blo(p1.y) + blo(p2.y) + blo(p3.y);
        a3 += bhi(p0.y) + bhi(p1.y) + bhi(p2.y) + bhi(p3.y);
      }
      for (; k + 4 <= m; k += 4) {
        uint2 p = wbr[__shfl(my, k + q) << 4];
        a0 += blo(p.x); a1 += bhi(p.x); a2 += blo(p.y); a3 += bhi(p.y);
      }
      if (k < m) {
        int rem = m - k;
        int i0 = __shfl(my, k + (q < rem ? q : 0));
        if (q < rem) {
          uint2 p = wbr[i0 << 4];
          a0 += blo(p.x); a1 += bhi(p.x); a2 += blo(p.y); a3 += bhi(p.y);
        }
      }
    }
    float inv = 1.0f / fmaxf((float)n, 1.0f);
    o0 += a0 * inv; o1 += a1 * inv; o2 += a2 * inv; o3 += a3 * inv;
  }
  o0 += __shfl_xor(o0, 16); o0 += __shfl_xor(o0, 32);
  o1 += __shfl_xor(o1, 16); o1 += __shfl_xor(o1, 32);
  o2 += __shfl_xor(o2, 16); o2 += __shfl_xor(o2, 32);
  o3 += __shfl_xor(o3, 16); o3 += __shfl_xor(o3, 32);
  if (q == 0) {
    float4 o; o.x = o0; o.y = o1; o.z = o2; o.w = o3;
    ((float4*)out)[(v << 4) + l16] = o;
  }
}

extern "C" void kernel_launch(void* const* d_in, const int* in_sizes, int n_in,
                              void* d_out, int out_size, void* d_ws, size_t ws_size,
                              hipStream_t stream) {
  const float* feat = (const float*)d_in[0];
  const float* W1   = (const float*)d_in[1];
  const float* b1   = (const float*)d_in[2];
  const float* W2   = (const float*)d_in[3];
  const float* b2   = (const float*)d_in[4];
  const int* es1 = (const int*)d_in[5];
  const int* ed1 = (const int*)d_in[6];
  const int* es2 = (const int*)d_in[7];
  const int* ed2 = (const int*)d_in[8];

  char* ws = (char*)d_ws;
  int* ghist           = (int*)(ws + 0);             // 460,992 B (counts)
  int* gpre            = (int*)(ws + 460992);        // 460,992 B (prefixes)
  int* btot            = (int*)(ws + 921984);        // 392 ints
  unsigned* sorted     = (unsigned*)(ws + 925184);   // 19.2 MB
  unsigned short* sorted2 = (unsigned short*)(ws + 20125184); // 9.6 MB
  int* offk            = (int*)(ws + 29725184);      // 2*200704 ints
  int* cntk            = (int*)(ws + 31330816);      // 2*200704 ints
  unsigned short* featb = (unsigned short*)(ws + 32936448);  // 12.8 MB
  unsigned short* s1m   = (unsigned short*)(ws + 45736448);  // 38.4 MB
  unsigned short* wh2   = (unsigned short*)(ws + 84136448);  // 19.2 MB
  unsigned short* w1t   = (unsigned short*)(ws + 103336448); // 98,304 B
  unsigned short* w2t   = (unsigned short*)(ws + 103434752); // 49,152 B

  prep_count_k<<<2 * NCH + 1635, 1024, 0, stream>>>(feat, W1, W2, ed1, ed2,
                                                    featb, w1t, w2t, ghist);
  scanb_k<<<2 * NB, 320, 0, stream>>>(ghist, gpre, btot);
  scatter_k<<<2 * NCH, 1024, 0, stream>>>(es1, ed1, es2, ed2, ghist, gpre,
                                          btot, sorted);
  sortb_k<<<2 * NB, 1024, 0, stream>>>(btot, sorted, sorted2, offk, cntk);
  agg1_k<<<3125, 256, 0, stream>>>(offk, cntk, sorted2, featb, s1m);
  gemm12_k<<<512, 512, 0, stream>>>(s1m, cntk, w1t, b1, w2t, b2, wh2);
  agg2f_k<<<12500, 256, 0, stream>>>(offk, cntk, sorted2, (const uint2*)wh2,
                                     (float*)d_out);
}